// Round 17
// baseline (86.489 us; speedup 1.0000x reference)
//
#include <hip/hip_runtime.h>
#include <math.h>

// DRR via Siddon ray tracing, 256^3 volume, 256x256 detector.
// Dual-chain ILP: 8 threads/ray, each thread traces TWO alpha-partitions
// (q and q+8) as interleaved independent merge state machines -> 2 loads in
// flight per thread and ~2x VALU issue per latency window, attacking the
// serial ADV->min3->midpoint->address->load dependency that single-chain
// pipelining (R7) could not break. Block = 128 threads = 16 consecutive rays
// (lane-fast) x 8 chain-pairs; wave = 16 rays x 4 partitions per chain
// (R10's proven footprint). Per-segment arithmetic bit-identical to R10
// (midpoint-trunc cells, reference-faithful rounding; range-checked advance).
// Unified peel: (pv,ps)=(0,0) makes the first consume an exact no-op.

#define NPLANE 256
constexpr int TPR = 16;

__device__ __forceinline__ float palpha(int i, float sp, float src, float rd) {
    return fmaf((float)i, sp, -src) * rd;
}

__device__ __forceinline__ void axis_setup(float SP, float SRC, float SDD, float RD,
                                           float lo, int& I, int& DI, float& NXT) {
    float q = fmaf(lo, SDD, SRC) / SP;
    q = fminf(fmaxf(q, -1.f), 257.f);
    if (SDD > 0.f) {
        DI = 1;
        I = (int)ceilf(q);
        while (I > 0 && palpha(I - 1, SP, SRC, RD) >= lo) --I;
        while (I <= NPLANE && palpha(I, SP, SRC, RD) < lo) ++I;
        NXT = (I <= NPLANE) ? palpha(I, SP, SRC, RD) : INFINITY;
    } else {
        DI = -1;
        I = (int)floorf(q);
        while (I < NPLANE && palpha(I + 1, SP, SRC, RD) >= lo) ++I;
        while (I >= 0 && palpha(I, SP, SRC, RD) < lo) --I;
        NXT = (I >= 0) ? palpha(I, SP, SRC, RD) : INFINITY;
    }
}

__global__ __launch_bounds__(128) void drr_kernel(
    const float* __restrict__ vol,
    const float* __restrict__ spacing,
    const float* __restrict__ sdrp,
    const float* __restrict__ rot,
    const float* __restrict__ trans,
    float* __restrict__ out)
{
    int tid = threadIdx.x;
    int q   = tid >> 4;                        // 0..7: chains q and q+8
    int rlo = tid & 15;                        // ray-in-block (fast)
    int rl  = ((int)blockIdx.x << 4) | rlo;    // 0..65535 linear ray id

    // R = Rz(theta) @ Ry(phi) @ Rx(gamma): columns 0 (ray dir), 1 (u), 2 (v)
    float theta = rot[0], phi = rot[1], gam = rot[2];
    float ct = cosf(theta), st = sinf(theta);
    float cp = cosf(phi),   sp_ = sinf(phi);
    float cg = cosf(gam),   sg = sinf(gam);

    float r0x = ct * cp, r0y = st * cp, r0z = -sp_;
    float ux = ct * sp_ * sg - st * cg, uy = st * sp_ * sg + ct * cg, uz = cp * sg;
    float vx = ct * sp_ * cg + st * sg, vy = st * sp_ * cg - ct * sg, vz = cp * cg;

    // lane-fast detector axis = least stride-weighted volume motion (uniform)
    float cost_u = fabsf(ux) * 65536.f + fabsf(uy) * 256.f + fabsf(uz);
    float cost_v = fabsf(vx) * 65536.f + fabsf(vy) * 256.f + fabsf(vz);
    bool tfast = cost_u < cost_v;
    int ti = tfast ? (rl & 255) : (rl >> 8);
    int si = tfast ? (rl >> 8) : (rl & 255);

    float sdr = sdrp[0];
    float tx = trans[0], ty = trans[1], tz = trans[2];

    float sx = sdr * r0x + tx,  sy = sdr * r0y + ty,  sz = sdr * r0z + tz;
    float cxx = -sdr * r0x + tx, cxy = -sdr * r0y + ty, cxz = -sdr * r0z + tz;

    float tval = (float)(ti - 127) * 2.0f;
    float sval = (float)(si - 127) * 2.0f;

    float gx = tval * ux + sval * vx + cxx;
    float gy = tval * uy + sval * vy + cxy;
    float gz = tval * uz + sval * vz + cxz;

    float sdx = gx - sx + 1e-8f;
    float sdy = gy - sy + 1e-8f;
    float sdz = gz - sz + 1e-8f;

    float spx = spacing[0], spy = spacing[1], spz = spacing[2];
    float rdx = 1.0f / sdx, rdy = 1.0f / sdy, rdz = 1.0f / sdz;

    float a0x = palpha(0, spx, sx, rdx), a1x = palpha(NPLANE, spx, sx, rdx);
    float a0y = palpha(0, spy, sy, rdy), a1y = palpha(NPLANE, spy, sy, rdy);
    float a0z = palpha(0, spz, sz, rdz), a1z = palpha(NPLANE, spz, sz, rdz);

    float amin = fmaxf(fmaxf(fminf(a0x, a1x), fminf(a0y, a1y)), fminf(a0z, a1z));
    float amax = fminf(fminf(fmaxf(a0x, a1x), fmaxf(a0y, a1y)), fmaxf(a0z, a1z));

    float acc = 0.f;

    if (amax > amin) {
        float range = amax - amin;
        constexpr float inv = 1.0f / (float)TPR;
        float ispx = 1.0f / spx, ispy = 1.0f / spy, ispz = 1.0f / spz;

        // ---- chain A state (partition q) ----
        int   ixA, iyA, izA, dixA, diyA, dizA;
        float nxxA, nxyA, nxzA, curA, endA, pvA = 0.f, psA = 0.f;
        {
            int p = q;
            float lo = fmaf(range, (float)p * inv, amin);
            float hi = (p == TPR - 1) ? INFINITY
                                      : fmaf(range, (float)(p + 1) * inv, amin);
            endA = fminf(hi, amax);
            axis_setup(spx, sx, sdx, rdx, lo, ixA, dixA, nxxA);
            axis_setup(spy, sy, sdy, rdy, lo, iyA, diyA, nxyA);
            axis_setup(spz, sz, sdz, rdz, lo, izA, dizA, nxzA);
            curA = fminf(fminf(nxxA, nxyA), nxzA);
        }
        // ---- chain B state (partition q+8) ----
        int   ixB, iyB, izB, dixB, diyB, dizB;
        float nxxB, nxyB, nxzB, curB, endB, pvB = 0.f, psB = 0.f;
        {
            int p = q + 8;
            float lo = fmaf(range, (float)p * inv, amin);
            float hi = (p == TPR - 1) ? INFINITY
                                      : fmaf(range, (float)(p + 1) * inv, amin);
            endB = fminf(hi, amax);
            axis_setup(spx, sx, sdx, rdx, lo, ixB, dixB, nxxB);
            axis_setup(spy, sy, sdy, rdy, lo, iyB, diyB, nxyB);
            axis_setup(spz, sz, sdz, rdz, lo, izB, dizB, nxzB);
            curB = fminf(fminf(nxxB, nxyB), nxzB);
        }

        bool actA = curA < endA;
        bool actB = curB < endB;

        // one interleaved step of a chain: advance merge, compute segment,
        // issue its load, consume the PREVIOUS load (depth-1 per chain).
        #define CHAIN_STEP(cur, end, nxx, nxy, nxz, ix, iy, iz, dix, diy, diz,     \
                           pv, ps, act)                                            \
        if (act) {                                                                 \
            if (nxx == cur) { ix += dix;                                           \
                nxx = ((unsigned)ix <= NPLANE) ? palpha(ix, spx, sx, rdx)          \
                                               : INFINITY; }                       \
            if (nxy == cur) { iy += diy;                                           \
                nxy = ((unsigned)iy <= NPLANE) ? palpha(iy, spy, sy, rdy)          \
                                               : INFINITY; }                       \
            if (nxz == cur) { iz += diz;                                           \
                nxz = ((unsigned)iz <= NPLANE) ? palpha(iz, spz, sz, rdz)          \
                                               : INFINITY; }                       \
            float nxt  = fminf(fminf(nxx, nxy), nxz);                              \
            float e    = fminf(nxt, amax);                                         \
            float amid = 0.5f * (cur + e);                                         \
            float pxv = fmaf(amid, sdx, sx) * ispx;                                \
            float pyv = fmaf(amid, sdy, sy) * ispy;                                \
            float pzv = fmaf(amid, sdz, sz) * ispz;                                \
            int jx = (int)pxv; jx = jx < 0 ? 0 : (jx > 255 ? 255 : jx);            \
            int jy = (int)pyv; jy = jy < 0 ? 0 : (jy > 255 ? 255 : jy);            \
            int jz = (int)pzv; jz = jz < 0 ? 0 : (jz > 255 ? 255 : jz);            \
            float nv = vol[(jx << 16) + (jy << 8) + jz];                           \
            acc = fmaf(pv, ps, acc);                                               \
            pv = nv; ps = e - cur;                                                 \
            cur = nxt;                                                             \
            act = cur < end;                                                       \
        }

        while (actA || actB) {
            CHAIN_STEP(curA, endA, nxxA, nxyA, nxzA, ixA, iyA, izA,
                       dixA, diyA, dizA, pvA, psA, actA)
            CHAIN_STEP(curB, endB, nxxB, nxyB, nxzB, ixB, iyB, izB,
                       dixB, diyB, dizB, pvB, psB, actB)
        }
        #undef CHAIN_STEP

        // drain the last in-flight segment of each chain (no-op if never run)
        acc = fmaf(pvA, psA, acc);
        acc = fmaf(pvB, psB, acc);
    }

    // reduction: shfl folds the wave's 4 chain-pairs (lanes r,r+16,r+32,r+48),
    // LDS folds the block's 2 waves.
    acc += __shfl_xor(acc, 16);
    acc += __shfl_xor(acc, 32);

    __shared__ float red[2][16];
    int wave = tid >> 6;                      // 0..1
    if ((tid & 63) < 16)
        red[wave][rlo] = acc;
    __syncthreads();

    if (tid < 16) {
        float s = red[0][tid] + red[1][tid];
        float rl2 = sqrtf(sdx * sdx + sdy * sdy + sdz * sdz);
        out[ti * 256 + si] = s * rl2;
    }
}

extern "C" void kernel_launch(void* const* d_in, const int* in_sizes, int n_in,
                              void* d_out, int out_size, void* d_ws, size_t ws_size,
                              hipStream_t stream) {
    const float* vol     = (const float*)d_in[0];
    const float* spacing = (const float*)d_in[1];
    const float* sdr     = (const float*)d_in[2];
    const float* rot     = (const float*)d_in[3];
    const float* trans   = (const float*)d_in[4];
    float* out = (float*)d_out;

    int nblocks = 256 * 256 / 16;   // 4096 blocks x 128 threads (16 rays each)
    drr_kernel<<<nblocks, 128, 0, stream>>>(vol, spacing, sdr, rot, trans, out);
}

// Round 18
// 54.427 us; speedup vs baseline: 1.5891x; 1.5891x over previous
//
#include <hip/hip_runtime.h>
#include <math.h>

// DRR via Siddon ray tracing, 256^3 volume, 256x256 detector.
// Final recombination of all proven-good pieces:
//  - 1M threads (TPR=16, ONE slice per thread): full TLP (R6/R10-proven;
//    halving threads regressed in R11).
//  - wave = 64 CONSECUTIVE rays x ONE partition: minimal cache footprint
//    (FETCH ~45MB, R8/R9/R11-proven) and minimal divergence (all lanes same
//    partition, adjacent rays -> near-identical segment counts).
//  - 512-thread blocks (8 waves): avoids R8's 16-wave scheduling quanta.
//  - reduction: one LDS fold of the block's 8 waves + 1 atomicAdd per block
//    (2 per output element, out zeroed by hipMemsetAsync; ~4MB write, ~3us).
// Inner loop bit-identical to R10 (midpoint-trunc cells, reference-faithful
// rounding; range-checked advance; depth-1 software pipeline).

#define NPLANE 256
constexpr int TPR = 16;

__device__ __forceinline__ float palpha(int i, float sp, float src, float rd) {
    return fmaf((float)i, sp, -src) * rd;
}

__global__ __launch_bounds__(512) void drr_kernel(
    const float* __restrict__ vol,
    const float* __restrict__ spacing,
    const float* __restrict__ sdrp,
    const float* __restrict__ rot,
    const float* __restrict__ trans,
    float* __restrict__ out)
{
    int tid  = threadIdx.x;
    int lane = tid & 63;                     // ray-in-group (fast)
    int wave = tid >> 6;                     // 0..7
    int b    = (int)blockIdx.x;
    int g    = b >> 1;                       // 64-ray group 0..1023
    int h    = b & 1;                        // partition half
    int part = (h << 3) | wave;              // 0..15
    int rl   = (g << 6) | lane;              // 0..65535 linear ray id

    // R = Rz(theta) @ Ry(phi) @ Rx(gamma): columns 0 (ray dir), 1 (u), 2 (v)
    float theta = rot[0], phi = rot[1], gam = rot[2];
    float ct = cosf(theta), st = sinf(theta);
    float cp = cosf(phi),   sp_ = sinf(phi);
    float cg = cosf(gam),   sg = sinf(gam);

    float r0x = ct * cp, r0y = st * cp, r0z = -sp_;
    float ux = ct * sp_ * sg - st * cg, uy = st * sp_ * sg + ct * cg, uz = cp * sg;
    float vx = ct * sp_ * cg + st * sg, vy = st * sp_ * cg - ct * sg, vz = cp * cg;

    // lane-fast detector axis = least stride-weighted volume motion (uniform)
    float cost_u = fabsf(ux) * 65536.f + fabsf(uy) * 256.f + fabsf(uz);
    float cost_v = fabsf(vx) * 65536.f + fabsf(vy) * 256.f + fabsf(vz);
    bool tfast = cost_u < cost_v;
    int ti = tfast ? (rl & 255) : (rl >> 8);
    int si = tfast ? (rl >> 8) : (rl & 255);

    float sdr = sdrp[0];
    float tx = trans[0], ty = trans[1], tz = trans[2];

    float sx = sdr * r0x + tx,  sy = sdr * r0y + ty,  sz = sdr * r0z + tz;
    float cxx = -sdr * r0x + tx, cxy = -sdr * r0y + ty, cxz = -sdr * r0z + tz;

    float tval = (float)(ti - 127) * 2.0f;
    float sval = (float)(si - 127) * 2.0f;

    float gx = tval * ux + sval * vx + cxx;
    float gy = tval * uy + sval * vy + cxy;
    float gz = tval * uz + sval * vz + cxz;

    float sdx = gx - sx + 1e-8f;
    float sdy = gy - sy + 1e-8f;
    float sdz = gz - sz + 1e-8f;

    float spx = spacing[0], spy = spacing[1], spz = spacing[2];
    float rdx = 1.0f / sdx, rdy = 1.0f / sdy, rdz = 1.0f / sdz;

    float a0x = palpha(0, spx, sx, rdx), a1x = palpha(NPLANE, spx, sx, rdx);
    float a0y = palpha(0, spy, sy, rdy), a1y = palpha(NPLANE, spy, sy, rdy);
    float a0z = palpha(0, spz, sz, rdz), a1z = palpha(NPLANE, spz, sz, rdz);

    float amin = fmaxf(fmaxf(fminf(a0x, a1x), fminf(a0y, a1y)), fminf(a0z, a1z));
    float amax = fminf(fminf(fmaxf(a0x, a1x), fmaxf(a0y, a1y)), fmaxf(a0z, a1z));

    float acc = 0.f;

    if (amax > amin) {
        float range = amax - amin;
        constexpr float inv = 1.0f / (float)TPR;
        float lo = fmaf(range, (float)part * inv, amin);
        float hi = (part == TPR - 1) ? INFINITY
                                     : fmaf(range, (float)(part + 1) * inv, amin);
        float end = fminf(hi, amax);

        int ix, iy, iz, dix, diy, diz;
        float nxx, nxy, nxz;

        // first plane crossing with alpha >= lo per axis
        #define SETUP(SP, SRC, SDD, RD, I, DI, NXT)                                \
        {                                                                          \
            float q = fmaf(lo, SDD, SRC) / (SP);                                   \
            q = fminf(fmaxf(q, -1.f), 257.f);                                      \
            if ((SDD) > 0.f) {                                                     \
                DI = 1;                                                            \
                I = (int)ceilf(q);                                                 \
                while (I > 0 && palpha(I - 1, SP, SRC, RD) >= lo) --I;             \
                while (I <= NPLANE && palpha(I, SP, SRC, RD) < lo) ++I;            \
                NXT = (I <= NPLANE) ? palpha(I, SP, SRC, RD) : INFINITY;           \
            } else {                                                               \
                DI = -1;                                                           \
                I = (int)floorf(q);                                                \
                while (I < NPLANE && palpha(I + 1, SP, SRC, RD) >= lo) ++I;        \
                while (I >= 0 && palpha(I, SP, SRC, RD) < lo) --I;                 \
                NXT = (I >= 0) ? palpha(I, SP, SRC, RD) : INFINITY;                \
            }                                                                      \
        }

        SETUP(spx, sx, sdx, rdx, ix, dix, nxx)
        SETUP(spy, sy, sdy, rdy, iy, diy, nxy)
        SETUP(spz, sz, sdz, rdz, iz, diz, nxz)
        #undef SETUP

        float ispx = 1.0f / spx, ispy = 1.0f / spy, ispz = 1.0f / spz;

        #define ADVANCE_MERGE()                                                    \
            if (nxx == cur) { ix += dix;                                           \
                nxx = ((unsigned)ix <= NPLANE) ? palpha(ix, spx, sx, rdx)          \
                                               : INFINITY; }                       \
            if (nxy == cur) { iy += diy;                                           \
                nxy = ((unsigned)iy <= NPLANE) ? palpha(iy, spy, sy, rdy)          \
                                               : INFINITY; }                       \
            if (nxz == cur) { iz += diz;                                           \
                nxz = ((unsigned)iz <= NPLANE) ? palpha(iz, spz, sz, rdz)          \
                                               : INFINITY; }

        #define SEG_ADDR(CUR, E, ADDR)                                             \
        {                                                                          \
            float amid = 0.5f * ((CUR) + (E));                                     \
            float pxv = fmaf(amid, sdx, sx) * ispx;                                \
            float pyv = fmaf(amid, sdy, sy) * ispy;                                \
            float pzv = fmaf(amid, sdz, sz) * ispz;                                \
            int jx = (int)pxv; jx = jx < 0 ? 0 : (jx > 255 ? 255 : jx);            \
            int jy = (int)pyv; jy = jy < 0 ? 0 : (jy > 255 ? 255 : jy);            \
            int jz = (int)pzv; jz = jz < 0 ? 0 : (jz > 255 ? 255 : jz);            \
            ADDR = (jx << 16) + (jy << 8) + jz;                                    \
        }

        float cur = fminf(fminf(nxx, nxy), nxz);

        if (cur < end) {
            // peel: compute segment 0, issue its load
            ADVANCE_MERGE();
            float nxt = fminf(fminf(nxx, nxy), nxz);
            float e   = fminf(nxt, amax);
            int addr; SEG_ADDR(cur, e, addr)
            float pstep = e - cur;
            float pval  = vol[addr];
            cur = nxt;

            while (cur < end) {
                // advance to segment n+1, issue its load while load n in flight
                ADVANCE_MERGE();
                nxt = fminf(fminf(nxx, nxy), nxz);
                e   = fminf(nxt, amax);
                int addr2; SEG_ADDR(cur, e, addr2)
                float nval = vol[addr2];           // issue (vmcnt grows)
                acc = fmaf(pval, pstep, acc);      // consume load n (vmcnt(1))
                pval  = nval;
                pstep = e - cur;
                cur = nxt;
            }
            acc = fmaf(pval, pstep, acc);          // drain
        }
        #undef ADVANCE_MERGE
        #undef SEG_ADDR
    }

    // fold the block's 8 waves (each lane = one ray), then one atomic per
    // block into out[ray] (2 atomics/output total; out zeroed by memset).
    __shared__ float red[8][64];
    red[wave][lane] = acc;
    __syncthreads();

    if (wave == 0) {
        float s = red[0][lane] + red[1][lane] + red[2][lane] + red[3][lane]
                + red[4][lane] + red[5][lane] + red[6][lane] + red[7][lane];
        if (s != 0.f) {
            float rl2 = sqrtf(sdx * sdx + sdy * sdy + sdz * sdz);
            atomicAdd(&out[ti * 256 + si], s * rl2);
        }
    }
}

extern "C" void kernel_launch(void* const* d_in, const int* in_sizes, int n_in,
                              void* d_out, int out_size, void* d_ws, size_t ws_size,
                              hipStream_t stream) {
    const float* vol     = (const float*)d_in[0];
    const float* spacing = (const float*)d_in[1];
    const float* sdr     = (const float*)d_in[2];
    const float* rot     = (const float*)d_in[3];
    const float* trans   = (const float*)d_in[4];
    float* out = (float*)d_out;

    hipMemsetAsync(out, 0, (size_t)out_size * sizeof(float), stream);

    int nblocks = 2048;   // 1024 ray-groups x 2 partition-halves, 512 thr/blk
    drr_kernel<<<nblocks, 512, 0, stream>>>(vol, spacing, sdr, rot, trans, out);
}